// Round 1
// baseline (1951.864 us; speedup 1.0000x reference)
//
#include <hip/hip_runtime.h>
#include <hip/hip_bf16.h>

#define BB 8
#define NN 4096
#define CIN 32
#define MM 1024
#define KNB 64
#define CAND 1024

// Exactly-rounded squared distance, numpy accumulation order, no FMA contraction.
__device__ __forceinline__ float sq3(float dx, float dy, float dz) {
    return __fadd_rn(__fadd_rn(__fmul_rn(dx, dx), __fmul_rn(dy, dy)), __fmul_rn(dz, dz));
}

// ---------------------------------------------------------------------------
// Kernel 1: farthest-point sampling, one block per cloud.
// Writes idx to ws, pos_out and batch_out directly to d_out.
// ---------------------------------------------------------------------------
__global__ __launch_bounds__(1024) void fps_kernel(
    const float* __restrict__ pos, int* __restrict__ idx_ws, float* __restrict__ out)
{
    const int b = blockIdx.x;
    const int t = threadIdx.x;
    __shared__ float plds[NN * 3];
    __shared__ int   chosen[MM];
    __shared__ float pv[16];
    __shared__ int   pi[16];
    __shared__ int   win;

    const float* P = pos + (size_t)b * NN * 3;
    for (int i = t; i < NN * 3; i += 1024) plds[i] = P[i];
    if (t == 0) { chosen[0] = 0; win = 0; }
    __syncthreads();

    float px[4], py[4], pz[4], dmin[4];
#pragma unroll
    for (int s = 0; s < 4; ++s) {
        int i = t + 1024 * s;
        px[s] = plds[3 * i];
        py[s] = plds[3 * i + 1];
        pz[s] = plds[3 * i + 2];
        dmin[s] = 1e10f;
    }

    for (int it = 1; it < MM; ++it) {
        int wi = win;
        float lx = plds[3 * wi], ly = plds[3 * wi + 1], lz = plds[3 * wi + 2];
        float bv = -1.0f;
        int   bi = 0x7fffffff;
#pragma unroll
        for (int s = 0; s < 4; ++s) {
            float dx = px[s] - lx, dy = py[s] - ly, dz = pz[s] - lz;
            float d = sq3(dx, dy, dz);
            float dm = fminf(dmin[s], d);
            dmin[s] = dm;
            // strict > keeps smallest s on tie; i ascends with s for fixed t
            if (dm > bv) { bv = dm; bi = t + 1024 * s; }
        }
        // wave(64) argmax reduce: larger value wins, tie -> smaller index
#pragma unroll
        for (int off = 32; off >= 1; off >>= 1) {
            float ov = __shfl_down(bv, off);
            int   oi = __shfl_down(bi, off);
            if (ov > bv || (ov == bv && oi < bi)) { bv = ov; bi = oi; }
        }
        if ((t & 63) == 0) { pv[t >> 6] = bv; pi[t >> 6] = bi; }
        __syncthreads();
        if (t < 64) {
            float v2 = (t < 16) ? pv[t] : -1.0f;
            int   i2 = (t < 16) ? pi[t] : 0x7fffffff;
#pragma unroll
            for (int off = 8; off >= 1; off >>= 1) {
                float ov = __shfl_down(v2, off);
                int   oi = __shfl_down(i2, off);
                if (ov > v2 || (ov == v2 && oi < i2)) { v2 = ov; i2 = oi; }
            }
            if (t == 0) { chosen[it] = i2; win = i2; }
        }
        __syncthreads();
    }

    // Outputs: idx to ws, pos_out + batch_out to d_out (M == blockDim)
    {
        int m  = t;
        int mi = chosen[m];
        idx_ws[b * MM + m] = mi;
        const int PO = BB * MM * 128;       // pos_out offset (floats)
        const int BO = PO + BB * MM * 3;    // batch_out offset
        int row = b * MM + m;
        out[PO + 3 * row + 0] = plds[3 * mi];
        out[PO + 3 * row + 1] = plds[3 * mi + 1];
        out[PO + 3 * row + 2] = plds[3 * mi + 2];
        out[BO + row] = (float)b;
    }
}

// ---------------------------------------------------------------------------
// Kernel 2: per-centroid ball query + rank-select top-64 + MLP + masked max.
// One block (256 threads) per centroid.
// ---------------------------------------------------------------------------
__global__ __launch_bounds__(256, 2) void sa_kernel(
    const float* __restrict__ x, const float* __restrict__ pos,
    const int* __restrict__ idx_ws,
    const float* __restrict__ W1, const float* __restrict__ b1,
    const float* __restrict__ W2, const float* __restrict__ b2,
    const float* __restrict__ W3, const float* __restrict__ b3,
    float* __restrict__ out)
{
    const int bm = blockIdx.x;            // 0..B*M-1
    const int b  = bm >> 10;              // M = 1024
    const int t  = threadIdx.x;

    __shared__ float cd2[CAND];
    __shared__ int   cid[CAND];
    __shared__ int   cnt;
    __shared__ int   sel[KNB];
    __shared__ float H0[64 * 36];         // 35 inputs + 1 pad, rows 16B-aligned
    __shared__ float H1[64 * 64];
    __shared__ float H2[64 * 64];
    __shared__ float part[4 * 128];

    const float R2 = (float)(0.2 * 0.2);  // matches JAX f64->f32 demotion
    const float* P = pos + (size_t)b * NN * 3;
    const int ci = idx_ws[bm];

    if (t == 0) cnt = 0;
    __syncthreads();

    const float cx = P[3 * ci], cy = P[3 * ci + 1], cz = P[3 * ci + 2];

    // ---- candidates within radius ----
    for (int i = t; i < NN; i += 256) {
        float dx = P[3 * i] - cx, dy = P[3 * i + 1] - cy, dz = P[3 * i + 2] - cz;
        float d2 = sq3(dx, dy, dz);
        if (d2 <= R2) {
            int p = atomicAdd(&cnt, 1);
            if (p < CAND) { cd2[p] = d2; cid[p] = i; }
        }
    }
    __syncthreads();
    const int n = min(cnt, CAND);
    const int V = min(n, KNB);

    // ---- exact rank selection: rank over strict total order (d2, idx) ----
    for (int i = t; i < n; i += 256) {
        float di = cd2[i];
        int   ii = cid[i];
        int rank = 0;
        for (int j = 0; j < n; ++j) {
            float dj = cd2[j];
            int   ij = cid[j];
            rank += (dj < di || (dj == di && ij < ii)) ? 1 : 0;
        }
        if (rank < KNB) sel[rank] = ii;
    }
    __syncthreads();

    // ---- gather H0 = [x_j (32) | pos_j - ctr (3) | pad] ----
    {
        int c = t & 31, kk = t >> 5;
        for (int k = kk; k < 64; k += 8) {
            float v = 0.0f;
            if (k < V) {
                int g = b * NN + sel[k];
                v = x[(size_t)g * CIN + c];
            }
            H0[k * 36 + c] = v;
            if (c < 4) {
                float rv = 0.0f;
                if (k < V && c < 3) {
                    int g2 = sel[k];
                    float cc = (c == 0) ? cx : (c == 1) ? cy : cz;
                    rv = P[3 * g2 + c] - cc;
                }
                H0[k * 36 + 32 + c] = rv;  // c==3 writes pad
            }
        }
    }
    __syncthreads();

    // ---- layer 1: [64,35] @ [35,64] + b1, relu ----
    {
        int c = t & 63, kg = t >> 6;
        float w[35];
#pragma unroll
        for (int r = 0; r < 35; ++r) w[r] = W1[r * 64 + c];
        float bb = b1[c];
        for (int k = kg * 16; k < kg * 16 + 16; ++k) {
            const float4* hp = (const float4*)(H0 + k * 36);
            float acc = bb;
#pragma unroll
            for (int r4 = 0; r4 < 8; ++r4) {
                float4 h = hp[r4];
                acc = fmaf(h.x, w[r4 * 4 + 0], acc);
                acc = fmaf(h.y, w[r4 * 4 + 1], acc);
                acc = fmaf(h.z, w[r4 * 4 + 2], acc);
                acc = fmaf(h.w, w[r4 * 4 + 3], acc);
            }
            float4 h = hp[8];
            acc = fmaf(h.x, w[32], acc);
            acc = fmaf(h.y, w[33], acc);
            acc = fmaf(h.z, w[34], acc);
            H1[k * 64 + c] = fmaxf(acc, 0.0f);
        }
    }
    __syncthreads();

    // ---- layer 2: [64,64] @ [64,64] + b2, relu ----
    {
        int c = t & 63, kg = t >> 6;
        float w[64];
#pragma unroll
        for (int r = 0; r < 64; ++r) w[r] = W2[r * 64 + c];
        float bb = b2[c];
        for (int k = kg * 16; k < kg * 16 + 16; ++k) {
            const float4* hp = (const float4*)(H1 + k * 64);
            float acc = bb;
#pragma unroll
            for (int r4 = 0; r4 < 16; ++r4) {
                float4 h = hp[r4];
                acc = fmaf(h.x, w[r4 * 4 + 0], acc);
                acc = fmaf(h.y, w[r4 * 4 + 1], acc);
                acc = fmaf(h.z, w[r4 * 4 + 2], acc);
                acc = fmaf(h.w, w[r4 * 4 + 3], acc);
            }
            H2[k * 64 + c] = fmaxf(acc, 0.0f);
        }
    }
    __syncthreads();

    // ---- layer 3 + masked max: out[j] = max_{k<V} (H2[k,:]@W3[:,j]) + b3[j] ----
    {
        int j = t & 63, kq = t >> 6;
        float wa[64], wb[64];
#pragma unroll
        for (int r = 0; r < 64; ++r) {
            wa[r] = W3[r * 128 + j];
            wb[r] = W3[r * 128 + 64 + j];
        }
        float ma = -1e10f, mb = -1e10f;
        int k0 = kq * 16;
        int k1 = min(k0 + 16, V);
        for (int k = k0; k < k1; ++k) {
            const float4* hp = (const float4*)(H2 + k * 64);
            float aa = 0.0f, ab = 0.0f;
#pragma unroll
            for (int r4 = 0; r4 < 16; ++r4) {
                float4 h = hp[r4];
                aa = fmaf(h.x, wa[r4 * 4 + 0], aa);
                aa = fmaf(h.y, wa[r4 * 4 + 1], aa);
                aa = fmaf(h.z, wa[r4 * 4 + 2], aa);
                aa = fmaf(h.w, wa[r4 * 4 + 3], aa);
                ab = fmaf(h.x, wb[r4 * 4 + 0], ab);
                ab = fmaf(h.y, wb[r4 * 4 + 1], ab);
                ab = fmaf(h.z, wb[r4 * 4 + 2], ab);
                ab = fmaf(h.w, wb[r4 * 4 + 3], ab);
            }
            ma = fmaxf(ma, aa);
            mb = fmaxf(mb, ab);
        }
        part[kq * 128 + j] = ma;
        part[kq * 128 + 64 + j] = mb;
    }
    __syncthreads();
    if (t < 128) {
        float v = fmaxf(fmaxf(part[t], part[128 + t]), fmaxf(part[256 + t], part[384 + t]));
        out[(size_t)bm * 128 + t] = v + b3[t];
    }
}

extern "C" void kernel_launch(void* const* d_in, const int* in_sizes, int n_in,
                              void* d_out, int out_size, void* d_ws, size_t ws_size,
                              hipStream_t stream) {
    const float* x   = (const float*)d_in[0];
    const float* pos = (const float*)d_in[1];
    // d_in[2] = batch (unused: layout is static)
    const float* W1 = (const float*)d_in[3];
    const float* b1 = (const float*)d_in[4];
    const float* W2 = (const float*)d_in[5];
    const float* b2 = (const float*)d_in[6];
    const float* W3 = (const float*)d_in[7];
    const float* b3 = (const float*)d_in[8];
    float* out   = (float*)d_out;
    int*   idx_ws = (int*)d_ws;

    hipLaunchKernelGGL(fps_kernel, dim3(BB), dim3(1024), 0, stream, pos, idx_ws, out);
    hipLaunchKernelGGL(sa_kernel, dim3(BB * MM), dim3(256), 0, stream,
                       x, pos, idx_ws, W1, b1, W2, b2, W3, b3, out);
}

// Round 2
// 1204.172 us; speedup vs baseline: 1.6209x; 1.6209x over previous
//
#include <hip/hip_runtime.h>
#include <hip/hip_bf16.h>

#define BB 8
#define NN 4096
#define CIN 32
#define MM 1024
#define KNB 64
#define CAND 1024
#define FPS_T 512
#define FPS_PPT 8   // NN / FPS_T

// Exactly-rounded squared distance, numpy accumulation order, no FMA contraction.
__device__ __forceinline__ float sq3(float dx, float dy, float dz) {
    return __fadd_rn(__fadd_rn(__fmul_rn(dx, dx), __fmul_rn(dy, dy)), __fmul_rn(dz, dz));
}

// One DPP max-combine step on a packed u64 key. old=self => invalid source
// lanes are a no-op for max. Runs in the VALU pipe (no LDS latency).
template<int CTRL>
__device__ __forceinline__ unsigned long long dpp_maxkey(unsigned long long k) {
    unsigned int lo = (unsigned int)k;
    unsigned int hi = (unsigned int)(k >> 32);
    unsigned int nlo = (unsigned int)__builtin_amdgcn_update_dpp((int)lo, (int)lo, CTRL, 0xF, 0xF, false);
    unsigned int nhi = (unsigned int)__builtin_amdgcn_update_dpp((int)hi, (int)hi, CTRL, 0xF, 0xF, false);
    unsigned long long nk = ((unsigned long long)nhi << 32) | (unsigned long long)nlo;
    return nk > k ? nk : k;
}

// ---------------------------------------------------------------------------
// Kernel 1: farthest-point sampling, one block (512 thr) per cloud.
// Key idea: u64 (d2_bits<<32 | ~idx) argmax; DPP in-wave reduce (rocPRIM
// wave64 sequence, result in lane 63); parity-buffered partials; ONE barrier
// per iteration; all threads redundantly combine the 8 partials.
// ---------------------------------------------------------------------------
__global__ __launch_bounds__(FPS_T) void fps_kernel(
    const float* __restrict__ pos, int* __restrict__ idx_ws, float* __restrict__ out)
{
    const int b = blockIdx.x;
    const int t = threadIdx.x;
    __shared__ float plds[NN * 3];
    __shared__ int   chosen[MM];
    __shared__ unsigned long long part[2][FPS_T / 64];

    const float* P = pos + (size_t)b * NN * 3;
    for (int i = t; i < NN * 3; i += FPS_T) plds[i] = P[i];
    if (t == 0) chosen[0] = 0;
    __syncthreads();

    float px[FPS_PPT], py[FPS_PPT], pz[FPS_PPT], dmin[FPS_PPT];
#pragma unroll
    for (int s = 0; s < FPS_PPT; ++s) {
        int i = t + FPS_T * s;
        px[s] = plds[3 * i];
        py[s] = plds[3 * i + 1];
        pz[s] = plds[3 * i + 2];
        dmin[s] = 1e10f;
    }

    int win = 0;
    for (int it = 1; it < MM; ++it) {
        const float lx = plds[3 * win], ly = plds[3 * win + 1], lz = plds[3 * win + 2];
        float bv = -1.0f;
        int   bi = 0;
#pragma unroll
        for (int s = 0; s < FPS_PPT; ++s) {
            float dx = px[s] - lx, dy = py[s] - ly, dz = pz[s] - lz;
            float d  = sq3(dx, dy, dz);
            float dm = fminf(dmin[s], d);
            dmin[s] = dm;
            // strict > keeps smallest s on tie; i ascends with s for fixed t
            if (dm > bv) { bv = dm; bi = t + FPS_T * s; }
        }
        // bv >= 0 here (dmin >= 0 and every thread owns 8 points), so float
        // bits are monotone as u32. max key => max d2, tie -> min idx
        // (matches numpy argmax first-max semantics).
        unsigned long long k =
            ((unsigned long long)__float_as_uint(bv) << 32) | (unsigned int)(~bi);
        k = dpp_maxkey<0x111>(k);  // row_shr:1
        k = dpp_maxkey<0x112>(k);  // row_shr:2
        k = dpp_maxkey<0x114>(k);  // row_shr:4
        k = dpp_maxkey<0x118>(k);  // row_shr:8
        k = dpp_maxkey<0x142>(k);  // row_bcast:15
        k = dpp_maxkey<0x143>(k);  // row_bcast:31
        if ((t & 63) == 63) part[it & 1][t >> 6] = k;
        __syncthreads();
        unsigned long long km = part[it & 1][0];
#pragma unroll
        for (int w2 = 1; w2 < FPS_T / 64; ++w2) {
            unsigned long long kk = part[it & 1][w2];
            km = kk > km ? kk : km;
        }
        win = (int)(~(unsigned int)km);
        if (t == 0) chosen[it] = win;
        // no second barrier: next iter writes the other parity slot; chosen[]
        // is only read after the final barrier below.
    }
    __syncthreads();

    // Outputs: idx to ws, pos_out + batch_out to d_out
    for (int m = t; m < MM; m += FPS_T) {
        int mi = chosen[m];
        idx_ws[b * MM + m] = mi;
        const int PO = BB * MM * 128;       // pos_out offset (floats)
        const int BO = PO + BB * MM * 3;    // batch_out offset
        int row = b * MM + m;
        out[PO + 3 * row + 0] = plds[3 * mi];
        out[PO + 3 * row + 1] = plds[3 * mi + 1];
        out[PO + 3 * row + 2] = plds[3 * mi + 2];
        out[BO + row] = (float)b;
    }
}

// ---------------------------------------------------------------------------
// Kernel 2: per-centroid ball query + rank-select top-64 + MLP + masked max.
// One block (256 threads) per centroid. (Unchanged from round 1.)
// ---------------------------------------------------------------------------
__global__ __launch_bounds__(256, 2) void sa_kernel(
    const float* __restrict__ x, const float* __restrict__ pos,
    const int* __restrict__ idx_ws,
    const float* __restrict__ W1, const float* __restrict__ b1,
    const float* __restrict__ W2, const float* __restrict__ b2,
    const float* __restrict__ W3, const float* __restrict__ b3,
    float* __restrict__ out)
{
    const int bm = blockIdx.x;            // 0..B*M-1
    const int b  = bm >> 10;              // M = 1024
    const int t  = threadIdx.x;

    __shared__ float cd2[CAND];
    __shared__ int   cid[CAND];
    __shared__ int   cnt;
    __shared__ int   sel[KNB];
    __shared__ float H0[64 * 36];         // 35 inputs + 1 pad, rows 16B-aligned
    __shared__ float H1[64 * 64];
    __shared__ float H2[64 * 64];
    __shared__ float part[4 * 128];

    const float R2 = (float)(0.2 * 0.2);  // matches JAX f64->f32 demotion
    const float* P = pos + (size_t)b * NN * 3;
    const int ci = idx_ws[bm];

    if (t == 0) cnt = 0;
    __syncthreads();

    const float cx = P[3 * ci], cy = P[3 * ci + 1], cz = P[3 * ci + 2];

    // ---- candidates within radius ----
    for (int i = t; i < NN; i += 256) {
        float dx = P[3 * i] - cx, dy = P[3 * i + 1] - cy, dz = P[3 * i + 2] - cz;
        float d2 = sq3(dx, dy, dz);
        if (d2 <= R2) {
            int p = atomicAdd(&cnt, 1);
            if (p < CAND) { cd2[p] = d2; cid[p] = i; }
        }
    }
    __syncthreads();
    const int n = min(cnt, CAND);
    const int V = min(n, KNB);

    // ---- exact rank selection: rank over strict total order (d2, idx) ----
    for (int i = t; i < n; i += 256) {
        float di = cd2[i];
        int   ii = cid[i];
        int rank = 0;
        for (int j = 0; j < n; ++j) {
            float dj = cd2[j];
            int   ij = cid[j];
            rank += (dj < di || (dj == di && ij < ii)) ? 1 : 0;
        }
        if (rank < KNB) sel[rank] = ii;
    }
    __syncthreads();

    // ---- gather H0 = [x_j (32) | pos_j - ctr (3) | pad] ----
    {
        int c = t & 31, kk = t >> 5;
        for (int k = kk; k < 64; k += 8) {
            float v = 0.0f;
            if (k < V) {
                int g = b * NN + sel[k];
                v = x[(size_t)g * CIN + c];
            }
            H0[k * 36 + c] = v;
            if (c < 4) {
                float rv = 0.0f;
                if (k < V && c < 3) {
                    int g2 = sel[k];
                    float cc = (c == 0) ? cx : (c == 1) ? cy : cz;
                    rv = P[3 * g2 + c] - cc;
                }
                H0[k * 36 + 32 + c] = rv;  // c==3 writes pad
            }
        }
    }
    __syncthreads();

    // ---- layer 1: [64,35] @ [35,64] + b1, relu ----
    {
        int c = t & 63, kg = t >> 6;
        float w[35];
#pragma unroll
        for (int r = 0; r < 35; ++r) w[r] = W1[r * 64 + c];
        float bb = b1[c];
        for (int k = kg * 16; k < kg * 16 + 16; ++k) {
            const float4* hp = (const float4*)(H0 + k * 36);
            float acc = bb;
#pragma unroll
            for (int r4 = 0; r4 < 8; ++r4) {
                float4 h = hp[r4];
                acc = fmaf(h.x, w[r4 * 4 + 0], acc);
                acc = fmaf(h.y, w[r4 * 4 + 1], acc);
                acc = fmaf(h.z, w[r4 * 4 + 2], acc);
                acc = fmaf(h.w, w[r4 * 4 + 3], acc);
            }
            float4 h = hp[8];
            acc = fmaf(h.x, w[32], acc);
            acc = fmaf(h.y, w[33], acc);
            acc = fmaf(h.z, w[34], acc);
            H1[k * 64 + c] = fmaxf(acc, 0.0f);
        }
    }
    __syncthreads();

    // ---- layer 2: [64,64] @ [64,64] + b2, relu ----
    {
        int c = t & 63, kg = t >> 6;
        float w[64];
#pragma unroll
        for (int r = 0; r < 64; ++r) w[r] = W2[r * 64 + c];
        float bb = b2[c];
        for (int k = kg * 16; k < kg * 16 + 16; ++k) {
            const float4* hp = (const float4*)(H1 + k * 64);
            float acc = bb;
#pragma unroll
            for (int r4 = 0; r4 < 16; ++r4) {
                float4 h = hp[r4];
                acc = fmaf(h.x, w[r4 * 4 + 0], acc);
                acc = fmaf(h.y, w[r4 * 4 + 1], acc);
                acc = fmaf(h.z, w[r4 * 4 + 2], acc);
                acc = fmaf(h.w, w[r4 * 4 + 3], acc);
            }
            H2[k * 64 + c] = fmaxf(acc, 0.0f);
        }
    }
    __syncthreads();

    // ---- layer 3 + masked max: out[j] = max_{k<V} (H2[k,:]@W3[:,j]) + b3[j] ----
    {
        int j = t & 63, kq = t >> 6;
        float wa[64], wb[64];
#pragma unroll
        for (int r = 0; r < 64; ++r) {
            wa[r] = W3[r * 128 + j];
            wb[r] = W3[r * 128 + 64 + j];
        }
        float ma = -1e10f, mb = -1e10f;
        int k0 = kq * 16;
        int k1 = min(k0 + 16, V);
        for (int k = k0; k < k1; ++k) {
            const float4* hp = (const float4*)(H2 + k * 64);
            float aa = 0.0f, ab = 0.0f;
#pragma unroll
            for (int r4 = 0; r4 < 16; ++r4) {
                float4 h = hp[r4];
                aa = fmaf(h.x, wa[r4 * 4 + 0], aa);
                aa = fmaf(h.y, wa[r4 * 4 + 1], aa);
                aa = fmaf(h.z, wa[r4 * 4 + 2], aa);
                aa = fmaf(h.w, wa[r4 * 4 + 3], aa);
                ab = fmaf(h.x, wb[r4 * 4 + 0], ab);
                ab = fmaf(h.y, wb[r4 * 4 + 1], ab);
                ab = fmaf(h.z, wb[r4 * 4 + 2], ab);
                ab = fmaf(h.w, wb[r4 * 4 + 3], ab);
            }
            ma = fmaxf(ma, aa);
            mb = fmaxf(mb, ab);
        }
        part[kq * 128 + j] = ma;
        part[kq * 128 + 64 + j] = mb;
    }
    __syncthreads();
    if (t < 128) {
        float v = fmaxf(fmaxf(part[t], part[128 + t]), fmaxf(part[256 + t], part[384 + t]));
        out[(size_t)bm * 128 + t] = v + b3[t];
    }
}

extern "C" void kernel_launch(void* const* d_in, const int* in_sizes, int n_in,
                              void* d_out, int out_size, void* d_ws, size_t ws_size,
                              hipStream_t stream) {
    const float* x   = (const float*)d_in[0];
    const float* pos = (const float*)d_in[1];
    // d_in[2] = batch (unused: layout is static)
    const float* W1 = (const float*)d_in[3];
    const float* b1 = (const float*)d_in[4];
    const float* W2 = (const float*)d_in[5];
    const float* b2 = (const float*)d_in[6];
    const float* W3 = (const float*)d_in[7];
    const float* b3 = (const float*)d_in[8];
    float* out   = (float*)d_out;
    int*   idx_ws = (int*)d_ws;

    hipLaunchKernelGGL(fps_kernel, dim3(BB), dim3(FPS_T), 0, stream, pos, idx_ws, out);
    hipLaunchKernelGGL(sa_kernel, dim3(BB * MM), dim3(256), 0, stream,
                       x, pos, idx_ws, W1, b1, W2, b2, W3, b3, out);
}

// Round 3
// 876.394 us; speedup vs baseline: 2.2272x; 1.3740x over previous
//
#include <hip/hip_runtime.h>
#include <hip/hip_bf16.h>

#define BB 8
#define NN 4096
#define CIN 32
#define MM 1024
#define KNB 64
#define CAND 1024
#define FPS_T 512
#define FPS_PPT 8   // NN / FPS_T
#define ROWS 72     // ushort row stride for H tiles (64 + 8 pad)

typedef __attribute__((ext_vector_type(8))) short  short8;
typedef __attribute__((ext_vector_type(4))) float  f32x4;

// Exactly-rounded squared distance, numpy accumulation order, no FMA contraction.
__device__ __forceinline__ float sq3(float dx, float dy, float dz) {
    return __fadd_rn(__fadd_rn(__fmul_rn(dx, dx), __fmul_rn(dy, dy)), __fmul_rn(dz, dz));
}

__device__ __forceinline__ unsigned short f2bf(float v) {
    union { __hip_bfloat16 b; unsigned short u; } cv;
    cv.b = __float2bfloat16(v);
    return cv.u;
}
__device__ __forceinline__ float bf2f(unsigned short u) {
    union { unsigned short u; __hip_bfloat16 b; } cv;
    cv.u = u;
    return __bfloat162float(cv.b);
}

static __device__ __forceinline__ f32x4 mfma16(short8 a, short8 b, f32x4 c) {
    return __builtin_amdgcn_mfma_f32_16x16x32_bf16(a, b, c, 0, 0, 0);
}

// One DPP max-combine step on a packed u64 key (rocPRIM wave64 pattern).
template<int CTRL>
__device__ __forceinline__ unsigned long long dpp_maxkey(unsigned long long k) {
    unsigned int lo = (unsigned int)k;
    unsigned int hi = (unsigned int)(k >> 32);
    unsigned int nlo = (unsigned int)__builtin_amdgcn_update_dpp((int)lo, (int)lo, CTRL, 0xF, 0xF, false);
    unsigned int nhi = (unsigned int)__builtin_amdgcn_update_dpp((int)hi, (int)hi, CTRL, 0xF, 0xF, false);
    unsigned long long nk = ((unsigned long long)nhi << 32) | (unsigned long long)nlo;
    return nk > k ? nk : k;
}

// ---------------------------------------------------------------------------
// Kernel 0: convert W1/W2/W3 into MFMA B-fragment-ready bf16 hi/lo planes.
// Frag element: B[k = kstep*32 + (lane>>4)*8 + j][n = tile*16 + (lane&15)]
// idx = (((tile*2 + kstep)*2 + h)*64 + lane)*8 + j,  h: 0=hi 1=lo.
// Layer bases (ushorts): L1=0 (4 tiles), L2=8192 (4 tiles), L3=16384 (8 tiles).
// ---------------------------------------------------------------------------
__global__ __launch_bounds__(256) void prep_kernel(
    const float* __restrict__ W1, const float* __restrict__ W2,
    const float* __restrict__ W3, unsigned short* __restrict__ wf)
{
    int gid = blockIdx.x * 256 + threadIdx.x;   // 0..4095 slots
    const float* W; int K, Ncol, base, slot;
    if (gid < 1024)      { W = W1; K = 35; Ncol = 64;  base = 0;     slot = gid; }
    else if (gid < 2048) { W = W2; K = 64; Ncol = 64;  base = 8192;  slot = gid - 1024; }
    else                 { W = W3; K = 64; Ncol = 128; base = 16384; slot = gid - 2048; }
    int lane = slot & 63, h = (slot >> 6) & 1, kstep = (slot >> 7) & 1, tile = slot >> 8;
    int col = tile * 16 + (lane & 15), quad = lane >> 4;
#pragma unroll
    for (int j = 0; j < 8; ++j) {
        int k = kstep * 32 + quad * 8 + j;
        float wv = (k < K) ? W[k * Ncol + col] : 0.0f;
        unsigned short hi = f2bf(wv);
        unsigned short v = h ? f2bf(wv - bf2f(hi)) : hi;
        wf[base + slot * 8 + j] = v;
    }
}

// ---------------------------------------------------------------------------
// Kernel 1: farthest-point sampling, one block (512 thr) per cloud.
// v3: float4 coords in LDS (1 b128 read), vectorized partial combine.
// ---------------------------------------------------------------------------
__global__ __launch_bounds__(FPS_T) void fps_kernel(
    const float* __restrict__ pos, int* __restrict__ idx_ws, float* __restrict__ out)
{
    const int b = blockIdx.x;
    const int t = threadIdx.x;
    __shared__ float4 plds4[NN];
    __shared__ int    chosen[MM];
    __shared__ __align__(16) unsigned long long part[2][FPS_T / 64];

    const float* P = pos + (size_t)b * NN * 3;
    for (int i = t; i < NN; i += FPS_T) {
        float4 v;
        v.x = P[3 * i]; v.y = P[3 * i + 1]; v.z = P[3 * i + 2]; v.w = 0.0f;
        plds4[i] = v;
    }
    if (t == 0) chosen[0] = 0;
    __syncthreads();

    float px[FPS_PPT], py[FPS_PPT], pz[FPS_PPT], dmin[FPS_PPT];
#pragma unroll
    for (int s = 0; s < FPS_PPT; ++s) {
        int i = t + FPS_T * s;
        float4 v = plds4[i];
        px[s] = v.x; py[s] = v.y; pz[s] = v.z;
        dmin[s] = 1e10f;
    }

    int win = 0;
    for (int it = 1; it < MM; ++it) {
        float4 wc = plds4[win];
        const float lx = wc.x, ly = wc.y, lz = wc.z;
        float bv = -1.0f;
        int   bi = 0;
#pragma unroll
        for (int s = 0; s < FPS_PPT; ++s) {
            float dx = px[s] - lx, dy = py[s] - ly, dz = pz[s] - lz;
            float d  = sq3(dx, dy, dz);
            float dm = fminf(dmin[s], d);
            dmin[s] = dm;
            if (dm > bv) { bv = dm; bi = t + FPS_T * s; }  // idx ascends with s
        }
        // d2 >= 0 so float bits monotone as u32; max key = max d2, tie -> min idx.
        unsigned long long k =
            ((unsigned long long)__float_as_uint(bv) << 32) | (unsigned int)(~bi);
        k = dpp_maxkey<0x111>(k);  // row_shr:1
        k = dpp_maxkey<0x112>(k);  // row_shr:2
        k = dpp_maxkey<0x114>(k);  // row_shr:4
        k = dpp_maxkey<0x118>(k);  // row_shr:8
        k = dpp_maxkey<0x142>(k);  // row_bcast:15
        k = dpp_maxkey<0x143>(k);  // row_bcast:31
        if ((t & 63) == 63) part[it & 1][t >> 6] = k;
        __syncthreads();
        const ulonglong2* pp = (const ulonglong2*)&part[it & 1][0];
        ulonglong2 p01 = pp[0], p23 = pp[1], p45 = pp[2], p67 = pp[3];
        unsigned long long km = p01.x;
        km = p01.y > km ? p01.y : km;
        km = p23.x > km ? p23.x : km;
        km = p23.y > km ? p23.y : km;
        km = p45.x > km ? p45.x : km;
        km = p45.y > km ? p45.y : km;
        km = p67.x > km ? p67.x : km;
        km = p67.y > km ? p67.y : km;
        win = (int)(~(unsigned int)km);
        if (t == 0) chosen[it] = win;
        // parity buffer: no second barrier needed
    }
    __syncthreads();

    for (int m = t; m < MM; m += FPS_T) {
        int mi = chosen[m];
        idx_ws[b * MM + m] = mi;
        const int PO = BB * MM * 128;       // pos_out offset (floats)
        const int BO = PO + BB * MM * 3;    // batch_out offset
        int row = b * MM + m;
        float4 c = plds4[mi];
        out[PO + 3 * row + 0] = c.x;
        out[PO + 3 * row + 1] = c.y;
        out[PO + 3 * row + 2] = c.z;
        out[BO + row] = (float)b;
    }
}

// ---------------------------------------------------------------------------
// Kernel 2: ball query + rank-select top-64 + bf16x3 MFMA MLP + masked max.
// One block (256 thr = 4 waves) per centroid. Wave w owns neighbor rows
// 16w..16w+15 end-to-end (gather -> L1 -> L2 -> L3): no barriers in the MLP.
// ---------------------------------------------------------------------------
__global__ __launch_bounds__(256, 3) void sa_kernel(
    const float* __restrict__ x, const float* __restrict__ pos,
    const int* __restrict__ idx_ws, const unsigned short* __restrict__ wf,
    const float* __restrict__ b1, const float* __restrict__ b2,
    const float* __restrict__ b3, float* __restrict__ out)
{
    const int bm = blockIdx.x;            // 0..B*M-1
    const int b  = bm >> 10;              // M = 1024
    const int t  = threadIdx.x;
    const int w    = t >> 6;              // wave 0..3
    const int lane = t & 63;

    __shared__ unsigned short HA[2 * 64 * ROWS];   // hi plane, then lo plane
    __shared__ unsigned short HB[2 * 64 * ROWS];
    __shared__ float cd2[CAND];
    __shared__ int   cid[CAND];
    __shared__ int   cnt;
    __shared__ int   sel[KNB];
    __shared__ float red[4][128];

    const float R2 = (float)(0.2 * 0.2);
    const float* P = pos + (size_t)b * NN * 3;
    const int ci = idx_ws[bm];

    if (t == 0) cnt = 0;
    // zero HA (H0 pad cols / invalid rows must be finite-zero)
    {
        short8 z = {};
        short8* z8 = (short8*)HA;
        for (int i = t; i < (2 * 64 * ROWS) / 8; i += 256) z8[i] = z;
    }

    const float cx = P[3 * ci], cy = P[3 * ci + 1], cz = P[3 * ci + 2];

    // ---- candidates within radius ----
    for (int i = t; i < NN; i += 256) {
        float dx = P[3 * i] - cx, dy = P[3 * i + 1] - cy, dz = P[3 * i + 2] - cz;
        float d2 = sq3(dx, dy, dz);
        if (d2 <= R2) {
            int p = atomicAdd(&cnt, 1);
            if (p < CAND) { cd2[p] = d2; cid[p] = i; }
        }
    }
    __syncthreads();
    const int n = min(cnt, CAND);
    const int V = min(n, KNB);

    // ---- exact rank selection over strict total order (d2, idx) ----
    for (int i = t; i < n; i += 256) {
        float di = cd2[i];
        int   ii = cid[i];
        int rank = 0;
        for (int j = 0; j < n; ++j) {
            float dj = cd2[j];
            int   ij = cid[j];
            rank += (dj < di || (dj == di && ij < ii)) ? 1 : 0;
        }
        if (rank < KNB) sel[rank] = ii;
    }
    __syncthreads();

    // ---- gather H0 (bf16 hi/lo): row = 16w + (lane&15), cols part*8..+7 ----
    {
        const int row  = 16 * w + (lane & 15);
        const int prt  = lane >> 4;
        if (row < V) {
            int g = b * NN + sel[row];
            const float4* xr = (const float4*)(x + (size_t)g * CIN + prt * 8);
            float4 v0 = xr[0], v1 = xr[1];
            float vv[8] = {v0.x, v0.y, v0.z, v0.w, v1.x, v1.y, v1.z, v1.w};
            short8 hv, lv;
#pragma unroll
            for (int j = 0; j < 8; ++j) {
                unsigned short h = f2bf(vv[j]);
                hv[j] = (short)h;
                lv[j] = (short)f2bf(vv[j] - bf2f(h));
            }
            *(short8*)(HA + row * ROWS + prt * 8) = hv;
            *(short8*)(HA + 64 * ROWS + row * ROWS + prt * 8) = lv;
            if (prt == 0) {
                int g2 = sel[row];
#pragma unroll
                for (int c = 0; c < 3; ++c) {
                    float cc = (c == 0) ? cx : (c == 1) ? cy : cz;
                    float rv = P[3 * g2 + c] - cc;
                    unsigned short h = f2bf(rv);
                    HA[row * ROWS + 32 + c] = h;
                    HA[64 * ROWS + row * ROWS + 32 + c] = f2bf(rv - bf2f(h));
                }
            }
        }
    }
    // no barrier: wave reads only its own strip below

    const int m16  = lane & 15;
    const int quad = lane >> 4;
    const int arow = 16 * w + m16;
    const short8* wf8 = (const short8*)wf;

    // ---- layer 1: H0[64x64(k-pad)] @ W1 -> HB, relu, bf16x3 ----
    {
        short8 aH[2], aL[2];
        aH[0] = *(const short8*)(HA + arow * ROWS + quad * 8);
        aH[1] = *(const short8*)(HA + arow * ROWS + 32 + quad * 8);
        aL[0] = *(const short8*)(HA + 64 * ROWS + arow * ROWS + quad * 8);
        aL[1] = *(const short8*)(HA + 64 * ROWS + arow * ROWS + 32 + quad * 8);
#pragma unroll
        for (int tile = 0; tile < 4; ++tile) {
            f32x4 acc = {};
#pragma unroll
            for (int ks = 0; ks < 2; ++ks) {
                short8 bH = wf8[((tile * 2 + ks) * 2 + 0) * 64 + lane];
                short8 bL = wf8[((tile * 2 + ks) * 2 + 1) * 64 + lane];
                acc = mfma16(aH[ks], bH, acc);
                acc = mfma16(aH[ks], bL, acc);
                acc = mfma16(aL[ks], bH, acc);
            }
            int col = tile * 16 + m16;
            float bb = b1[col];
#pragma unroll
            for (int i = 0; i < 4; ++i) {
                int grow = 16 * w + quad * 4 + i;
                float v = fmaxf(acc[i] + bb, 0.0f);
                unsigned short h = f2bf(v);
                HB[grow * ROWS + col] = h;
                HB[64 * ROWS + grow * ROWS + col] = f2bf(v - bf2f(h));
            }
        }
    }

    // ---- layer 2: HB @ W2 -> HA (overwrite own strip), relu ----
    {
        short8 aH[2], aL[2];
        aH[0] = *(const short8*)(HB + arow * ROWS + quad * 8);
        aH[1] = *(const short8*)(HB + arow * ROWS + 32 + quad * 8);
        aL[0] = *(const short8*)(HB + 64 * ROWS + arow * ROWS + quad * 8);
        aL[1] = *(const short8*)(HB + 64 * ROWS + arow * ROWS + 32 + quad * 8);
#pragma unroll
        for (int tile = 0; tile < 4; ++tile) {
            f32x4 acc = {};
#pragma unroll
            for (int ks = 0; ks < 2; ++ks) {
                short8 bH = wf8[1024 + ((tile * 2 + ks) * 2 + 0) * 64 + lane];
                short8 bL = wf8[1024 + ((tile * 2 + ks) * 2 + 1) * 64 + lane];
                acc = mfma16(aH[ks], bH, acc);
                acc = mfma16(aH[ks], bL, acc);
                acc = mfma16(aL[ks], bH, acc);
            }
            int col = tile * 16 + m16;
            float bb = b2[col];
#pragma unroll
            for (int i = 0; i < 4; ++i) {
                int grow = 16 * w + quad * 4 + i;
                float v = fmaxf(acc[i] + bb, 0.0f);
                unsigned short h = f2bf(v);
                HA[grow * ROWS + col] = h;
                HA[64 * ROWS + grow * ROWS + col] = f2bf(v - bf2f(h));
            }
        }
    }

    // ---- layer 3: HA @ W3 (no bias yet), masked strip-max ----
    {
        short8 aH[2], aL[2];
        aH[0] = *(const short8*)(HA + arow * ROWS + quad * 8);
        aH[1] = *(const short8*)(HA + arow * ROWS + 32 + quad * 8);
        aL[0] = *(const short8*)(HA + 64 * ROWS + arow * ROWS + quad * 8);
        aL[1] = *(const short8*)(HA + 64 * ROWS + arow * ROWS + 32 + quad * 8);
#pragma unroll
        for (int tile = 0; tile < 8; ++tile) {
            f32x4 acc = {};
#pragma unroll
            for (int ks = 0; ks < 2; ++ks) {
                short8 bH = wf8[2048 + ((tile * 2 + ks) * 2 + 0) * 64 + lane];
                short8 bL = wf8[2048 + ((tile * 2 + ks) * 2 + 1) * 64 + lane];
                acc = mfma16(aH[ks], bH, acc);
                acc = mfma16(aH[ks], bL, acc);
                acc = mfma16(aL[ks], bH, acc);
            }
            float mv = -1e10f;
#pragma unroll
            for (int i = 0; i < 4; ++i) {
                int grow = 16 * w + quad * 4 + i;   // neighbor index
                float v = (grow < V) ? acc[i] : -1e10f;
                mv = fmaxf(mv, v);
            }
            mv = fmaxf(mv, __shfl_xor(mv, 16));
            mv = fmaxf(mv, __shfl_xor(mv, 32));
            if (lane < 16) red[w][tile * 16 + lane] = mv;
        }
    }
    __syncthreads();

    if (t < 128) {
        float v = fmaxf(fmaxf(red[0][t], red[1][t]), fmaxf(red[2][t], red[3][t]));
        out[(size_t)bm * 128 + t] = v + b3[t];
    }
}

extern "C" void kernel_launch(void* const* d_in, const int* in_sizes, int n_in,
                              void* d_out, int out_size, void* d_ws, size_t ws_size,
                              hipStream_t stream) {
    const float* x   = (const float*)d_in[0];
    const float* pos = (const float*)d_in[1];
    const float* W1 = (const float*)d_in[3];
    const float* b1 = (const float*)d_in[4];
    const float* W2 = (const float*)d_in[5];
    const float* b2 = (const float*)d_in[6];
    const float* W3 = (const float*)d_in[7];
    const float* b3 = (const float*)d_in[8];
    float* out    = (float*)d_out;
    int*   idx_ws = (int*)d_ws;
    unsigned short* wf = (unsigned short*)((char*)d_ws + 32768);

    hipLaunchKernelGGL(prep_kernel, dim3(16), dim3(256), 0, stream, W1, W2, W3, wf);
    hipLaunchKernelGGL(fps_kernel, dim3(BB), dim3(FPS_T), 0, stream, pos, idx_ws, out);
    hipLaunchKernelGGL(sa_kernel, dim3(BB * MM), dim3(256), 0, stream,
                       x, pos, idx_ws, wf, b1, b2, b3, out);
}

// Round 4
// 799.696 us; speedup vs baseline: 2.4408x; 1.0959x over previous
//
#include <hip/hip_runtime.h>
#include <hip/hip_bf16.h>

#define BB 8
#define NN 4096
#define CIN 32
#define MM 1024
#define KNB 64
#define CAND 1024
#define FPS_T 256
#define FPS_PPT 16  // NN / FPS_T
#define ROWS 72     // ushort row stride for H tiles (64 + 8 pad)

typedef __attribute__((ext_vector_type(8))) short  short8;
typedef __attribute__((ext_vector_type(4))) float  f32x4;

// Exactly-rounded squared distance, numpy accumulation order, no FMA contraction.
__device__ __forceinline__ float sq3(float dx, float dy, float dz) {
    return __fadd_rn(__fadd_rn(__fmul_rn(dx, dx), __fmul_rn(dy, dy)), __fmul_rn(dz, dz));
}

__device__ __forceinline__ unsigned short f2bf(float v) {
    union { __hip_bfloat16 b; unsigned short u; } cv;
    cv.b = __float2bfloat16(v);
    return cv.u;
}
__device__ __forceinline__ float bf2f(unsigned short u) {
    union { unsigned short u; __hip_bfloat16 b; } cv;
    cv.u = u;
    return __bfloat162float(cv.b);
}

static __device__ __forceinline__ f32x4 mfma16(short8 a, short8 b, f32x4 c) {
    return __builtin_amdgcn_mfma_f32_16x16x32_bf16(a, b, c, 0, 0, 0);
}

// One DPP max-combine step on a packed u64 key (rocPRIM wave64 pattern).
template<int CTRL>
__device__ __forceinline__ unsigned long long dpp_maxkey(unsigned long long k) {
    unsigned int lo = (unsigned int)k;
    unsigned int hi = (unsigned int)(k >> 32);
    unsigned int nlo = (unsigned int)__builtin_amdgcn_update_dpp((int)lo, (int)lo, CTRL, 0xF, 0xF, false);
    unsigned int nhi = (unsigned int)__builtin_amdgcn_update_dpp((int)hi, (int)hi, CTRL, 0xF, 0xF, false);
    unsigned long long nk = ((unsigned long long)nhi << 32) | (unsigned long long)nlo;
    return nk > k ? nk : k;
}

// ---------------------------------------------------------------------------
// Kernel 0: convert W1/W2/W3 into MFMA B-fragment-ready bf16 hi/lo planes.
// Frag element: B[k = kstep*32 + (lane>>4)*8 + j][n = tile*16 + (lane&15)]
// idx = (((tile*2 + kstep)*2 + h)*64 + lane)*8 + j,  h: 0=hi 1=lo.
// Layer bases (ushorts): L1=0 (4 tiles), L2=8192 (4 tiles), L3=16384 (8 tiles).
// ---------------------------------------------------------------------------
__global__ __launch_bounds__(256) void prep_kernel(
    const float* __restrict__ W1, const float* __restrict__ W2,
    const float* __restrict__ W3, unsigned short* __restrict__ wf)
{
    int gid = blockIdx.x * 256 + threadIdx.x;   // 0..4095 slots
    const float* W; int K, Ncol, base, slot;
    if (gid < 1024)      { W = W1; K = 35; Ncol = 64;  base = 0;     slot = gid; }
    else if (gid < 2048) { W = W2; K = 64; Ncol = 64;  base = 8192;  slot = gid - 1024; }
    else                 { W = W3; K = 64; Ncol = 128; base = 16384; slot = gid - 2048; }
    int lane = slot & 63, h = (slot >> 6) & 1, kstep = (slot >> 7) & 1, tile = slot >> 8;
    int col = tile * 16 + (lane & 15), quad = lane >> 4;
#pragma unroll
    for (int j = 0; j < 8; ++j) {
        int k = kstep * 32 + quad * 8 + j;
        float wv = (k < K) ? W[k * Ncol + col] : 0.0f;
        unsigned short hi = f2bf(wv);
        unsigned short v = h ? f2bf(wv - bf2f(hi)) : hi;
        wf[base + slot * 8 + j] = v;
    }
}

// ---------------------------------------------------------------------------
// Kernel 1: farthest-point sampling, one block (256 thr = 4 waves, one wave
// per SIMD) per cloud. 16 pts/thread. Minimal reduce overhead: DPP in-wave
// reduce -> 4 u64 partials -> 2 b128 broadcast reads -> register tournament.
// One barrier per iteration (parity-buffered partials).
// ---------------------------------------------------------------------------
__global__ __launch_bounds__(FPS_T) void fps_kernel(
    const float* __restrict__ pos, int* __restrict__ idx_ws, float* __restrict__ out)
{
    const int b = blockIdx.x;
    const int t = threadIdx.x;
    __shared__ float4 plds4[NN];
    __shared__ int    chosen[MM];
    __shared__ __align__(16) unsigned long long part[2][FPS_T / 64];

    const float* P = pos + (size_t)b * NN * 3;
    for (int i = t; i < NN; i += FPS_T) {
        float4 v;
        v.x = P[3 * i]; v.y = P[3 * i + 1]; v.z = P[3 * i + 2]; v.w = 0.0f;
        plds4[i] = v;
    }
    if (t == 0) chosen[0] = 0;
    __syncthreads();

    float px[FPS_PPT], py[FPS_PPT], pz[FPS_PPT], dmin[FPS_PPT];
#pragma unroll
    for (int s = 0; s < FPS_PPT; ++s) {
        int i = t + FPS_T * s;
        float4 v = plds4[i];
        px[s] = v.x; py[s] = v.y; pz[s] = v.z;
        dmin[s] = 1e10f;
    }

    int win = 0;
    for (int it = 1; it < MM; ++it) {
        float4 wc = plds4[win];
        const float lx = wc.x, ly = wc.y, lz = wc.z;
        float bv = -1.0f;
        int   bi = 0;
#pragma unroll
        for (int s = 0; s < FPS_PPT; ++s) {
            float dx = px[s] - lx, dy = py[s] - ly, dz = pz[s] - lz;
            float d  = sq3(dx, dy, dz);
            float dm = fminf(dmin[s], d);
            dmin[s] = dm;
            if (dm > bv) { bv = dm; bi = t + FPS_T * s; }  // idx ascends with s
        }
        // d2 >= 0 so float bits monotone as u32; max key = max d2, tie -> min idx.
        unsigned long long k =
            ((unsigned long long)__float_as_uint(bv) << 32) | (unsigned int)(~bi);
        k = dpp_maxkey<0x111>(k);  // row_shr:1
        k = dpp_maxkey<0x112>(k);  // row_shr:2
        k = dpp_maxkey<0x114>(k);  // row_shr:4
        k = dpp_maxkey<0x118>(k);  // row_shr:8
        k = dpp_maxkey<0x142>(k);  // row_bcast:15
        k = dpp_maxkey<0x143>(k);  // row_bcast:31  -> lane 63 has wave max
        if ((t & 63) == 63) part[it & 1][t >> 6] = k;
        __syncthreads();
        const ulonglong2* pp = (const ulonglong2*)&part[it & 1][0];
        ulonglong2 p01 = pp[0], p23 = pp[1];
        unsigned long long ka = p01.x > p01.y ? p01.x : p01.y;
        unsigned long long kb = p23.x > p23.y ? p23.x : p23.y;
        unsigned long long km = ka > kb ? ka : kb;
        win = (int)(~(unsigned int)km);
        if (t == 0) chosen[it] = win;
        // parity buffer: no second barrier needed
    }
    __syncthreads();

    for (int m = t; m < MM; m += FPS_T) {
        int mi = chosen[m];
        idx_ws[b * MM + m] = mi;
        const int PO = BB * MM * 128;       // pos_out offset (floats)
        const int BO = PO + BB * MM * 3;    // batch_out offset
        int row = b * MM + m;
        float4 c = plds4[mi];
        out[PO + 3 * row + 0] = c.x;
        out[PO + 3 * row + 1] = c.y;
        out[PO + 3 * row + 2] = c.z;
        out[BO + row] = (float)b;
    }
}

// ---------------------------------------------------------------------------
// Kernel 2: ball query + rank-select top-64 + bf16x3 MFMA MLP + masked max.
// One block (256 thr = 4 waves) per centroid. Wave w owns neighbor rows
// 16w..16w+15 end-to-end; all layers write back in place into HA (the wave
// loads its full strip into registers before writing): no barriers in the
// MLP, single H buffer, no LDS zero pass -> ~29 KB LDS, 4 blocks/CU.
// ---------------------------------------------------------------------------
__global__ __launch_bounds__(256, 4) void sa_kernel(
    const float* __restrict__ x, const float* __restrict__ pos,
    const int* __restrict__ idx_ws, const unsigned short* __restrict__ wf,
    const float* __restrict__ b1, const float* __restrict__ b2,
    const float* __restrict__ b3, float* __restrict__ out)
{
    const int bm = blockIdx.x;            // 0..B*M-1
    const int b  = bm >> 10;              // M = 1024
    const int t  = threadIdx.x;
    const int w    = t >> 6;              // wave 0..3
    const int lane = t & 63;

    __shared__ unsigned short HA[2 * 64 * ROWS];   // hi plane, then lo plane
    __shared__ float cd2[CAND];
    __shared__ int   cid[CAND];
    __shared__ int   cnt;
    __shared__ int   sel[KNB];
    __shared__ float red[4][128];

    const float R2 = (float)(0.2 * 0.2);
    const float* P = pos + (size_t)b * NN * 3;
    const int ci = idx_ws[bm];

    if (t == 0) cnt = 0;
    __syncthreads();

    const float cx = P[3 * ci], cy = P[3 * ci + 1], cz = P[3 * ci + 2];

    // ---- candidates within radius ----
    for (int i = t; i < NN; i += 256) {
        float dx = P[3 * i] - cx, dy = P[3 * i + 1] - cy, dz = P[3 * i + 2] - cz;
        float d2 = sq3(dx, dy, dz);
        if (d2 <= R2) {
            int p = atomicAdd(&cnt, 1);
            if (p < CAND) { cd2[p] = d2; cid[p] = i; }
        }
    }
    __syncthreads();
    const int n = min(cnt, CAND);
    const int V = min(n, KNB);

    // ---- exact rank selection over strict total order (d2, idx) ----
    for (int i = t; i < n; i += 256) {
        float di = cd2[i];
        int   ii = cid[i];
        int rank = 0;
        for (int j = 0; j < n; ++j) {
            float dj = cd2[j];
            int   ij = cid[j];
            rank += (dj < di || (dj == di && ij < ii)) ? 1 : 0;
        }
        if (rank < KNB) sel[rank] = ii;
    }
    __syncthreads();

    // ---- gather H0 (bf16 hi/lo) + zero k-pad cols 32..63 ----
    // row = 16w + (lane&15); 4 lanes (prt=lane>>4) per row.
    {
        const int row = 16 * w + (lane & 15);
        const int prt = lane >> 4;
        short8 z = {};
        *(short8*)(HA + row * ROWS + 32 + prt * 8) = z;             // hi pad
        *(short8*)(HA + 64 * ROWS + row * ROWS + 32 + prt * 8) = z; // lo pad
        if (row < V) {
            int g = b * NN + sel[row];
            const float4* xr = (const float4*)(x + (size_t)g * CIN + prt * 8);
            float4 v0 = xr[0], v1 = xr[1];
            float vv[8] = {v0.x, v0.y, v0.z, v0.w, v1.x, v1.y, v1.z, v1.w};
            short8 hv, lv;
#pragma unroll
            for (int j = 0; j < 8; ++j) {
                unsigned short h = f2bf(vv[j]);
                hv[j] = (short)h;
                lv[j] = (short)f2bf(vv[j] - bf2f(h));
            }
            *(short8*)(HA + row * ROWS + prt * 8) = hv;
            *(short8*)(HA + 64 * ROWS + row * ROWS + prt * 8) = lv;
            if (prt == 0) {   // rel coords overwrite cols 32..34 (same thread
                int g2 = sel[row];  // that zeroed 32..39: program order safe)
#pragma unroll
                for (int c = 0; c < 3; ++c) {
                    float cc = (c == 0) ? cx : (c == 1) ? cy : cz;
                    float rv = P[3 * g2 + c] - cc;
                    unsigned short h = f2bf(rv);
                    HA[row * ROWS + 32 + c] = h;
                    HA[64 * ROWS + row * ROWS + 32 + c] = f2bf(rv - bf2f(h));
                }
            }
        }
    }
    // no barrier: wave reads only its own strip below

    const int m16  = lane & 15;
    const int quad = lane >> 4;
    const int arow = 16 * w + m16;
    const short8* wf8 = (const short8*)wf;

    // ---- layer 1: H0 @ W1 -> HA in place, relu, bf16x3 ----
    {
        short8 aH[2], aL[2];
        aH[0] = *(const short8*)(HA + arow * ROWS + quad * 8);
        aH[1] = *(const short8*)(HA + arow * ROWS + 32 + quad * 8);
        aL[0] = *(const short8*)(HA + 64 * ROWS + arow * ROWS + quad * 8);
        aL[1] = *(const short8*)(HA + 64 * ROWS + arow * ROWS + 32 + quad * 8);
#pragma unroll
        for (int tile = 0; tile < 4; ++tile) {
            f32x4 acc = {};
#pragma unroll
            for (int ks = 0; ks < 2; ++ks) {
                short8 bH = wf8[((tile * 2 + ks) * 2 + 0) * 64 + lane];
                short8 bL = wf8[((tile * 2 + ks) * 2 + 1) * 64 + lane];
                acc = mfma16(aH[ks], bH, acc);
                acc = mfma16(aH[ks], bL, acc);
                acc = mfma16(aL[ks], bH, acc);
            }
            int col = tile * 16 + m16;
            float bb = b1[col];
#pragma unroll
            for (int i = 0; i < 4; ++i) {
                int grow = 16 * w + quad * 4 + i;
                float v = fmaxf(acc[i] + bb, 0.0f);
                unsigned short h = f2bf(v);
                HA[grow * ROWS + col] = h;
                HA[64 * ROWS + grow * ROWS + col] = f2bf(v - bf2f(h));
            }
        }
    }

    // ---- layer 2: H1 @ W2 -> HA in place, relu ----
    {
        short8 aH[2], aL[2];
        aH[0] = *(const short8*)(HA + arow * ROWS + quad * 8);
        aH[1] = *(const short8*)(HA + arow * ROWS + 32 + quad * 8);
        aL[0] = *(const short8*)(HA + 64 * ROWS + arow * ROWS + quad * 8);
        aL[1] = *(const short8*)(HA + 64 * ROWS + arow * ROWS + 32 + quad * 8);
#pragma unroll
        for (int tile = 0; tile < 4; ++tile) {
            f32x4 acc = {};
#pragma unroll
            for (int ks = 0; ks < 2; ++ks) {
                short8 bH = wf8[1024 + ((tile * 2 + ks) * 2 + 0) * 64 + lane];
                short8 bL = wf8[1024 + ((tile * 2 + ks) * 2 + 1) * 64 + lane];
                acc = mfma16(aH[ks], bH, acc);
                acc = mfma16(aH[ks], bL, acc);
                acc = mfma16(aL[ks], bH, acc);
            }
            int col = tile * 16 + m16;
            float bb = b2[col];
#pragma unroll
            for (int i = 0; i < 4; ++i) {
                int grow = 16 * w + quad * 4 + i;
                float v = fmaxf(acc[i] + bb, 0.0f);
                unsigned short h = f2bf(v);
                HA[grow * ROWS + col] = h;
                HA[64 * ROWS + grow * ROWS + col] = f2bf(v - bf2f(h));
            }
        }
    }

    // ---- layer 3: H2 @ W3 (bias deferred), masked strip-max ----
    {
        short8 aH[2], aL[2];
        aH[0] = *(const short8*)(HA + arow * ROWS + quad * 8);
        aH[1] = *(const short8*)(HA + arow * ROWS + 32 + quad * 8);
        aL[0] = *(const short8*)(HA + 64 * ROWS + arow * ROWS + quad * 8);
        aL[1] = *(const short8*)(HA + 64 * ROWS + arow * ROWS + 32 + quad * 8);
#pragma unroll
        for (int tile = 0; tile < 8; ++tile) {
            f32x4 acc = {};
#pragma unroll
            for (int ks = 0; ks < 2; ++ks) {
                short8 bH = wf8[2048 + ((tile * 2 + ks) * 2 + 0) * 64 + lane];
                short8 bL = wf8[2048 + ((tile * 2 + ks) * 2 + 1) * 64 + lane];
                acc = mfma16(aH[ks], bH, acc);
                acc = mfma16(aH[ks], bL, acc);
                acc = mfma16(aL[ks], bH, acc);
            }
            float mv = -1e10f;
#pragma unroll
            for (int i = 0; i < 4; ++i) {
                int grow = 16 * w + quad * 4 + i;   // neighbor index
                float v = (grow < V) ? acc[i] : -1e10f;
                mv = fmaxf(mv, v);
            }
            mv = fmaxf(mv, __shfl_xor(mv, 16));
            mv = fmaxf(mv, __shfl_xor(mv, 32));
            if (lane < 16) red[w][tile * 16 + lane] = mv;
        }
    }
    __syncthreads();

    if (t < 128) {
        float v = fmaxf(fmaxf(red[0][t], red[1][t]), fmaxf(red[2][t], red[3][t]));
        out[(size_t)bm * 128 + t] = v + b3[t];
    }
}

extern "C" void kernel_launch(void* const* d_in, const int* in_sizes, int n_in,
                              void* d_out, int out_size, void* d_ws, size_t ws_size,
                              hipStream_t stream) {
    const float* x   = (const float*)d_in[0];
    const float* pos = (const float*)d_in[1];
    const float* W1 = (const float*)d_in[3];
    const float* b1 = (const float*)d_in[4];
    const float* W2 = (const float*)d_in[5];
    const float* b2 = (const float*)d_in[6];
    const float* W3 = (const float*)d_in[7];
    const float* b3 = (const float*)d_in[8];
    float* out    = (float*)d_out;
    int*   idx_ws = (int*)d_ws;
    unsigned short* wf = (unsigned short*)((char*)d_ws + 32768);

    hipLaunchKernelGGL(prep_kernel, dim3(16), dim3(256), 0, stream, W1, W2, W3, wf);
    hipLaunchKernelGGL(fps_kernel, dim3(BB), dim3(FPS_T), 0, stream, pos, idx_ws, out);
    hipLaunchKernelGGL(sa_kernel, dim3(BB * MM), dim3(256), 0, stream,
                       x, pos, idx_ws, wf, b1, b2, b3, out);
}

// Round 5
// 793.607 us; speedup vs baseline: 2.4595x; 1.0077x over previous
//
#include <hip/hip_runtime.h>
#include <hip/hip_bf16.h>

#define BB 8
#define NN 4096
#define CIN 32
#define MM 1024
#define KNB 64
#define CAND 1024
#define FPS_T 256
#define FPS_PPT 16  // NN / FPS_T
#define ROWS 72     // ushort row stride for H tiles (64 + 8 pad)

typedef __attribute__((ext_vector_type(8))) short  short8;
typedef __attribute__((ext_vector_type(4))) float  f32x4;
typedef __attribute__((ext_vector_type(2))) float  f32x2;

// Exactly-rounded squared distance, numpy accumulation order, no FMA contraction.
__device__ __forceinline__ float sq3(float dx, float dy, float dz) {
    return __fadd_rn(__fadd_rn(__fmul_rn(dx, dx), __fmul_rn(dy, dy)), __fmul_rn(dz, dz));
}

__device__ __forceinline__ unsigned short f2bf(float v) {
    union { __hip_bfloat16 b; unsigned short u; } cv;
    cv.b = __float2bfloat16(v);
    return cv.u;
}
__device__ __forceinline__ float bf2f(unsigned short u) {
    union { unsigned short u; __hip_bfloat16 b; } cv;
    cv.u = u;
    return __bfloat162float(cv.b);
}

static __device__ __forceinline__ f32x4 mfma16(short8 a, short8 b, f32x4 c) {
    return __builtin_amdgcn_mfma_f32_16x16x32_bf16(a, b, c, 0, 0, 0);
}

// One DPP max-combine step on a packed u64 key (rocPRIM wave64 pattern).
template<int CTRL>
__device__ __forceinline__ unsigned long long dpp_maxkey(unsigned long long k) {
    unsigned int lo = (unsigned int)k;
    unsigned int hi = (unsigned int)(k >> 32);
    unsigned int nlo = (unsigned int)__builtin_amdgcn_update_dpp((int)lo, (int)lo, CTRL, 0xF, 0xF, false);
    unsigned int nhi = (unsigned int)__builtin_amdgcn_update_dpp((int)hi, (int)hi, CTRL, 0xF, 0xF, false);
    unsigned long long nk = ((unsigned long long)nhi << 32) | (unsigned long long)nlo;
    return nk > k ? nk : k;
}

// ---------------------------------------------------------------------------
// Kernel 0: convert W1/W2/W3 into MFMA B-fragment-ready bf16 hi/lo planes.
// Frag element: B[k = kstep*32 + (lane>>4)*8 + j][n = tile*16 + (lane&15)]
// idx = (((tile*2 + kstep)*2 + h)*64 + lane)*8 + j,  h: 0=hi 1=lo.
// Layer bases (ushorts): L1=0 (4 tiles), L2=8192 (4 tiles), L3=16384 (8 tiles).
// ---------------------------------------------------------------------------
__global__ __launch_bounds__(256) void prep_kernel(
    const float* __restrict__ W1, const float* __restrict__ W2,
    const float* __restrict__ W3, unsigned short* __restrict__ wf)
{
    int gid = blockIdx.x * 256 + threadIdx.x;   // 0..4095 slots
    const float* W; int K, Ncol, base, slot;
    if (gid < 1024)      { W = W1; K = 35; Ncol = 64;  base = 0;     slot = gid; }
    else if (gid < 2048) { W = W2; K = 64; Ncol = 64;  base = 8192;  slot = gid - 1024; }
    else                 { W = W3; K = 64; Ncol = 128; base = 16384; slot = gid - 2048; }
    int lane = slot & 63, h = (slot >> 6) & 1, kstep = (slot >> 7) & 1, tile = slot >> 8;
    int col = tile * 16 + (lane & 15), quad = lane >> 4;
#pragma unroll
    for (int j = 0; j < 8; ++j) {
        int k = kstep * 32 + quad * 8 + j;
        float wv = (k < K) ? W[k * Ncol + col] : 0.0f;
        unsigned short hi = f2bf(wv);
        unsigned short v = h ? f2bf(wv - bf2f(hi)) : hi;
        wf[base + slot * 8 + j] = v;
    }
}

// ---------------------------------------------------------------------------
// Kernel 1: farthest-point sampling, one block (256 thr = 4 waves) per cloud.
// 16 pts/thread stored as 8 float2 pairs; distance update via packed-fp32
// VOP3P ops (contract(off) keeps exact per-component IEEE order). DPP wave
// reduce -> 4 u64 partials -> b128 broadcast reads -> register tournament.
// One barrier per iteration (parity-buffered partials).
// ---------------------------------------------------------------------------
__global__ __launch_bounds__(FPS_T) void fps_kernel(
    const float* __restrict__ pos, int* __restrict__ idx_ws, float* __restrict__ out)
{
    const int b = blockIdx.x;
    const int t = threadIdx.x;
    __shared__ float4 plds4[NN];
    __shared__ int    chosen[MM];
    __shared__ __align__(16) unsigned long long part[2][FPS_T / 64];

    const float* P = pos + (size_t)b * NN * 3;
    for (int i = t; i < NN; i += FPS_T) {
        float4 v;
        v.x = P[3 * i]; v.y = P[3 * i + 1]; v.z = P[3 * i + 2]; v.w = 0.0f;
        plds4[i] = v;
    }
    if (t == 0) chosen[0] = 0;
    __syncthreads();

    // pair s holds points i0 = t + 512*s (.x) and i0 + 256 (.y)
    f32x2 pxv[8], pyv[8], pzv[8], dminv[8];
#pragma unroll
    for (int s = 0; s < 8; ++s) {
        float4 a = plds4[t + 512 * s];
        float4 c = plds4[t + 512 * s + 256];
        pxv[s] = (f32x2){a.x, c.x};
        pyv[s] = (f32x2){a.y, c.y};
        pzv[s] = (f32x2){a.z, c.z};
        dminv[s] = (f32x2){1e10f, 1e10f};
    }

    int win = 0;
    for (int it = 1; it < MM; ++it) {
        float4 wc = plds4[win];
        const f32x2 lxv = (f32x2){wc.x, wc.x};
        const f32x2 lyv = (f32x2){wc.y, wc.y};
        const f32x2 lzv = (f32x2){wc.z, wc.z};
        float bv = -1.0f;
        int   bi = 0;
#pragma unroll
        for (int s = 0; s < 8; ++s) {
            f32x2 d;
            {
#pragma clang fp contract(off)
                f32x2 dx = pxv[s] - lxv;
                f32x2 dy = pyv[s] - lyv;
                f32x2 dz = pzv[s] - lzv;
                d = dx * dx + dy * dy + dz * dz;   // ((x2+y2)+z2), no FMA
            }
            float m0 = fminf(dminv[s].x, d.x);
            float m1 = fminf(dminv[s].y, d.y);
            dminv[s].x = m0;
            dminv[s].y = m1;
            // strict >: first-max priority; indices ascend (.x before .y)
            if (m0 > bv) { bv = m0; bi = t + 512 * s; }
            if (m1 > bv) { bv = m1; bi = t + 512 * s + 256; }
        }
        // d2 >= 0 so float bits monotone as u32; max key = max d2, tie -> min idx.
        unsigned long long k =
            ((unsigned long long)__float_as_uint(bv) << 32) | (unsigned int)(~bi);
        k = dpp_maxkey<0x111>(k);  // row_shr:1
        k = dpp_maxkey<0x112>(k);  // row_shr:2
        k = dpp_maxkey<0x114>(k);  // row_shr:4
        k = dpp_maxkey<0x118>(k);  // row_shr:8
        k = dpp_maxkey<0x142>(k);  // row_bcast:15
        k = dpp_maxkey<0x143>(k);  // row_bcast:31  -> lane 63 has wave max
        if ((t & 63) == 63) part[it & 1][t >> 6] = k;
        __syncthreads();
        const ulonglong2* pp = (const ulonglong2*)&part[it & 1][0];
        ulonglong2 p01 = pp[0], p23 = pp[1];
        unsigned long long ka = p01.x > p01.y ? p01.x : p01.y;
        unsigned long long kb = p23.x > p23.y ? p23.x : p23.y;
        unsigned long long km = ka > kb ? ka : kb;
        win = (int)(~(unsigned int)km);
        if (t == 0) chosen[it] = win;
        // parity buffer: no second barrier needed
    }
    __syncthreads();

    for (int m = t; m < MM; m += FPS_T) {
        int mi = chosen[m];
        idx_ws[b * MM + m] = mi;
        const int PO = BB * MM * 128;       // pos_out offset (floats)
        const int BO = PO + BB * MM * 3;    // batch_out offset
        int row = b * MM + m;
        float4 c = plds4[mi];
        out[PO + 3 * row + 0] = c.x;
        out[PO + 3 * row + 1] = c.y;
        out[PO + 3 * row + 2] = c.z;
        out[BO + row] = (float)b;
    }
}

// ---------------------------------------------------------------------------
// Kernel 2: ball query + rank-select top-64 + bf16x3 MFMA MLP + masked max.
// One block (256 thr = 4 waves) per centroid. v5: wave-ballot compaction
// (1 LDS atomic per wave-chunk instead of ~137 serialized), candidates packed
// as u64 (d2_bits<<32|idx) so the O(n^2) rank loop is 1 ds_read_b64 + 1
// u64-cmp per j. Wave w owns rows 16w..16w+15 end-to-end; in-place HA; no
// barriers inside the MLP.
// ---------------------------------------------------------------------------
__global__ __launch_bounds__(256, 4) void sa_kernel(
    const float* __restrict__ x, const float* __restrict__ pos,
    const int* __restrict__ idx_ws, const unsigned short* __restrict__ wf,
    const float* __restrict__ b1, const float* __restrict__ b2,
    const float* __restrict__ b3, float* __restrict__ out)
{
    const int bm = blockIdx.x;            // 0..B*M-1
    const int b  = bm >> 10;              // M = 1024
    const int t  = threadIdx.x;
    const int w    = t >> 6;              // wave 0..3
    const int lane = t & 63;

    __shared__ unsigned short HA[2 * 64 * ROWS];   // hi plane, then lo plane
    __shared__ unsigned long long candk[CAND];     // (d2_bits<<32)|idx
    __shared__ int   cnt;
    __shared__ int   sel[KNB];
    __shared__ float red[4][128];

    const float R2 = (float)(0.2 * 0.2);
    const float* P = pos + (size_t)b * NN * 3;
    const int ci = idx_ws[bm];

    if (t == 0) cnt = 0;
    __syncthreads();

    const float cx = P[3 * ci], cy = P[3 * ci + 1], cz = P[3 * ci + 2];

    // ---- candidates within radius: wave-ballot compaction ----
    for (int i = t; i < NN; i += 256) {
        float dx = P[3 * i] - cx, dy = P[3 * i + 1] - cy, dz = P[3 * i + 2] - cz;
        float d2 = sq3(dx, dy, dz);
        bool hit = d2 <= R2;
        unsigned long long m = __ballot(hit);
        if (m) {
            int leader = __ffsll((unsigned long long)m) - 1;
            int base = 0;
            if (lane == leader) base = atomicAdd(&cnt, __popcll(m));
            base = __shfl(base, leader);
            if (hit) {
                int p = base + __popcll(m & ((1ull << lane) - 1));
                if (p < CAND)
                    candk[p] = ((unsigned long long)__float_as_uint(d2) << 32)
                             | (unsigned int)i;
            }
        }
    }
    __syncthreads();
    const int n = min(cnt, CAND);
    const int V = min(n, KNB);

    // ---- exact rank selection: u64 key order == (d2, idx) lexicographic ----
    for (int i = t; i < n; i += 256) {
        unsigned long long ki = candk[i];
        int rank = 0;
        for (int j = 0; j < n; ++j)
            rank += (candk[j] < ki) ? 1 : 0;
        if (rank < KNB) sel[rank] = (int)(ki & 0xffffffffu);
    }
    __syncthreads();

    // ---- gather H0 (bf16 hi/lo) + zero k-pad cols 32..63 ----
    // row = 16w + (lane&15); 4 lanes (prt=lane>>4) per row.
    {
        const int row = 16 * w + (lane & 15);
        const int prt = lane >> 4;
        short8 z = {};
        *(short8*)(HA + row * ROWS + 32 + prt * 8) = z;             // hi pad
        *(short8*)(HA + 64 * ROWS + row * ROWS + 32 + prt * 8) = z; // lo pad
        if (row < V) {
            int g = b * NN + sel[row];
            const float4* xr = (const float4*)(x + (size_t)g * CIN + prt * 8);
            float4 v0 = xr[0], v1 = xr[1];
            float vv[8] = {v0.x, v0.y, v0.z, v0.w, v1.x, v1.y, v1.z, v1.w};
            short8 hv, lv;
#pragma unroll
            for (int j = 0; j < 8; ++j) {
                unsigned short h = f2bf(vv[j]);
                hv[j] = (short)h;
                lv[j] = (short)f2bf(vv[j] - bf2f(h));
            }
            *(short8*)(HA + row * ROWS + prt * 8) = hv;
            *(short8*)(HA + 64 * ROWS + row * ROWS + prt * 8) = lv;
            if (prt == 0) {   // rel coords overwrite cols 32..34 (same thread
                int g2 = sel[row];  // that zeroed 32..39: program order safe)
#pragma unroll
                for (int c = 0; c < 3; ++c) {
                    float cc = (c == 0) ? cx : (c == 1) ? cy : cz;
                    float rv = P[3 * g2 + c] - cc;
                    unsigned short h = f2bf(rv);
                    HA[row * ROWS + 32 + c] = h;
                    HA[64 * ROWS + row * ROWS + 32 + c] = f2bf(rv - bf2f(h));
                }
            }
        }
    }
    // no barrier: wave reads only its own strip below

    const int m16  = lane & 15;
    const int quad = lane >> 4;
    const int arow = 16 * w + m16;
    const short8* wf8 = (const short8*)wf;

    // ---- layer 1: H0 @ W1 -> HA in place, relu, bf16x3 ----
    {
        short8 aH[2], aL[2];
        aH[0] = *(const short8*)(HA + arow * ROWS + quad * 8);
        aH[1] = *(const short8*)(HA + arow * ROWS + 32 + quad * 8);
        aL[0] = *(const short8*)(HA + 64 * ROWS + arow * ROWS + quad * 8);
        aL[1] = *(const short8*)(HA + 64 * ROWS + arow * ROWS + 32 + quad * 8);
#pragma unroll
        for (int tile = 0; tile < 4; ++tile) {
            f32x4 acc = {};
#pragma unroll
            for (int ks = 0; ks < 2; ++ks) {
                short8 bH = wf8[((tile * 2 + ks) * 2 + 0) * 64 + lane];
                short8 bL = wf8[((tile * 2 + ks) * 2 + 1) * 64 + lane];
                acc = mfma16(aH[ks], bH, acc);
                acc = mfma16(aH[ks], bL, acc);
                acc = mfma16(aL[ks], bH, acc);
            }
            int col = tile * 16 + m16;
            float bb = b1[col];
#pragma unroll
            for (int i = 0; i < 4; ++i) {
                int grow = 16 * w + quad * 4 + i;
                float v = fmaxf(acc[i] + bb, 0.0f);
                unsigned short h = f2bf(v);
                HA[grow * ROWS + col] = h;
                HA[64 * ROWS + grow * ROWS + col] = f2bf(v - bf2f(h));
            }
        }
    }

    // ---- layer 2: H1 @ W2 -> HA in place, relu ----
    {
        short8 aH[2], aL[2];
        aH[0] = *(const short8*)(HA + arow * ROWS + quad * 8);
        aH[1] = *(const short8*)(HA + arow * ROWS + 32 + quad * 8);
        aL[0] = *(const short8*)(HA + 64 * ROWS + arow * ROWS + quad * 8);
        aL[1] = *(const short8*)(HA + 64 * ROWS + arow * ROWS + 32 + quad * 8);
#pragma unroll
        for (int tile = 0; tile < 4; ++tile) {
            f32x4 acc = {};
#pragma unroll
            for (int ks = 0; ks < 2; ++ks) {
                short8 bH = wf8[1024 + ((tile * 2 + ks) * 2 + 0) * 64 + lane];
                short8 bL = wf8[1024 + ((tile * 2 + ks) * 2 + 1) * 64 + lane];
                acc = mfma16(aH[ks], bH, acc);
                acc = mfma16(aH[ks], bL, acc);
                acc = mfma16(aL[ks], bH, acc);
            }
            int col = tile * 16 + m16;
            float bb = b2[col];
#pragma unroll
            for (int i = 0; i < 4; ++i) {
                int grow = 16 * w + quad * 4 + i;
                float v = fmaxf(acc[i] + bb, 0.0f);
                unsigned short h = f2bf(v);
                HA[grow * ROWS + col] = h;
                HA[64 * ROWS + grow * ROWS + col] = f2bf(v - bf2f(h));
            }
        }
    }

    // ---- layer 3: H2 @ W3 (bias deferred), masked strip-max ----
    {
        short8 aH[2], aL[2];
        aH[0] = *(const short8*)(HA + arow * ROWS + quad * 8);
        aH[1] = *(const short8*)(HA + arow * ROWS + 32 + quad * 8);
        aL[0] = *(const short8*)(HA + 64 * ROWS + arow * ROWS + quad * 8);
        aL[1] = *(const short8*)(HA + 64 * ROWS + arow * ROWS + 32 + quad * 8);
#pragma unroll
        for (int tile = 0; tile < 8; ++tile) {
            f32x4 acc = {};
#pragma unroll
            for (int ks = 0; ks < 2; ++ks) {
                short8 bH = wf8[2048 + ((tile * 2 + ks) * 2 + 0) * 64 + lane];
                short8 bL = wf8[2048 + ((tile * 2 + ks) * 2 + 1) * 64 + lane];
                acc = mfma16(aH[ks], bH, acc);
                acc = mfma16(aH[ks], bL, acc);
                acc = mfma16(aL[ks], bH, acc);
            }
            float mv = -1e10f;
#pragma unroll
            for (int i = 0; i < 4; ++i) {
                int grow = 16 * w + quad * 4 + i;   // neighbor index
                float v = (grow < V) ? acc[i] : -1e10f;
                mv = fmaxf(mv, v);
            }
            mv = fmaxf(mv, __shfl_xor(mv, 16));
            mv = fmaxf(mv, __shfl_xor(mv, 32));
            if (lane < 16) red[w][tile * 16 + lane] = mv;
        }
    }
    __syncthreads();

    if (t < 128) {
        float v = fmaxf(fmaxf(red[0][t], red[1][t]), fmaxf(red[2][t], red[3][t]));
        out[(size_t)bm * 128 + t] = v + b3[t];
    }
}

extern "C" void kernel_launch(void* const* d_in, const int* in_sizes, int n_in,
                              void* d_out, int out_size, void* d_ws, size_t ws_size,
                              hipStream_t stream) {
    const float* x   = (const float*)d_in[0];
    const float* pos = (const float*)d_in[1];
    const float* W1 = (const float*)d_in[3];
    const float* b1 = (const float*)d_in[4];
    const float* W2 = (const float*)d_in[5];
    const float* b2 = (const float*)d_in[6];
    const float* W3 = (const float*)d_in[7];
    const float* b3 = (const float*)d_in[8];
    float* out    = (float*)d_out;
    int*   idx_ws = (int*)d_ws;
    unsigned short* wf = (unsigned short*)((char*)d_ws + 32768);

    hipLaunchKernelGGL(prep_kernel, dim3(16), dim3(256), 0, stream, W1, W2, W3, wf);
    hipLaunchKernelGGL(fps_kernel, dim3(BB), dim3(FPS_T), 0, stream, pos, idx_ws, out);
    hipLaunchKernelGGL(sa_kernel, dim3(BB * MM), dim3(256), 0, stream,
                       x, pos, idx_ws, wf, b1, b2, b3, out);
}